// Round 1
// baseline (1945.218 us; speedup 1.0000x reference)
//
#include <hip/hip_runtime.h>

#define KD 64
#define UD 16
#define TH 30
#define NT 256

#define OUTER4P(ACC, A4, C4) \
  ACC[0][0] += A4.x * C4.x; ACC[0][1] += A4.x * C4.y; ACC[0][2] += A4.x * C4.z; ACC[0][3] += A4.x * C4.w; \
  ACC[1][0] += A4.y * C4.x; ACC[1][1] += A4.y * C4.y; ACC[1][2] += A4.y * C4.z; ACC[1][3] += A4.y * C4.w; \
  ACC[2][0] += A4.z * C4.x; ACC[2][1] += A4.z * C4.y; ACC[2][2] += A4.z * C4.z; ACC[2][3] += A4.z * C4.w; \
  ACC[3][0] += A4.w * C4.x; ACC[3][1] += A4.w * C4.y; ACC[3][2] += A4.w * C4.z; ACC[3][3] += A4.w * C4.w;

#define OUTER4M(ACC, A4, C4) \
  ACC[0][0] -= A4.x * C4.x; ACC[0][1] -= A4.x * C4.y; ACC[0][2] -= A4.x * C4.z; ACC[0][3] -= A4.x * C4.w; \
  ACC[1][0] -= A4.y * C4.x; ACC[1][1] -= A4.y * C4.y; ACC[1][2] -= A4.y * C4.z; ACC[1][3] -= A4.y * C4.w; \
  ACC[2][0] -= A4.z * C4.x; ACC[2][1] -= A4.z * C4.y; ACC[2][2] -= A4.z * C4.z; ACC[2][3] -= A4.z * C4.w; \
  ACC[3][0] -= A4.w * C4.x; ACC[3][1] -= A4.w * C4.y; ACC[3][2] -= A4.w * C4.z; ACC[3][3] -= A4.w * C4.w;

__global__ __launch_bounds__(NT, 2) void lqr_fp32(
    const float* __restrict__ gA, const float* __restrict__ gB,
    const float* __restrict__ gQ, const float* __restrict__ gR,
    const float* __restrict__ gG, float* __restrict__ gOut, int bsz)
{
  const int b   = blockIdx.x;
  const int tid = threadIdx.x;
  const int tx  = tid & 15;   // 0..15
  const int ty  = tid >> 4;   // 0..15

  // All big tiles stride-64: every hot-loop read is "row k fixed, lanes vary
  // along the row" -> conflict-free without padding. V is symmetric, so
  // V[i][k] is read as sV[k][i] (row-wise).
  __shared__ float sA[KD][KD];      // A
  __shared__ float sV[KD][KD];      // V (symmetric)
  __shared__ float sW[KD][KD];      // W = V*A   (also goals staging at init)
  __shared__ float sB[KD][UD];      // B
  __shared__ float sVB[KD][UD];     // V*B
  __shared__ float sBtW[UD][KD];    // B^T W = B^T V A
  __shared__ float sKg[UD][68];     // cols 0..63: Kg, col 64: kg
  __shared__ float sQG[TH + 1][KD]; // Q @ goals[t]
  __shared__ float sVuu[UD][17];
  __shared__ float sMT[UD][17];     // rows = columns of L^{-1}
  __shared__ float sVI[UD][17];     // Vuu^{-1}
  __shared__ float sv[KD];
  __shared__ float sBtv[UD];

  const size_t bb = (size_t)b;
  const float* Ab = gA + bb * (KD * KD);
  const float* Bb = gB + bb * (KD * UD);
  const float* Qb = gQ + bb * (KD * KD);
  const float* Rb = gR + bb * (UD * UD);
  const float* Gb = gG + bb * ((TH + 1) * KD);

  // ---- stage A, V(=Q), B, goals(->sW temp) ----
  for (int idx = tid; idx < KD * KD; idx += NT) {
    sA[idx >> 6][idx & 63] = Ab[idx];
    sV[idx >> 6][idx & 63] = Qb[idx];
  }
  for (int idx = tid; idx < KD * UD; idx += NT)
    (&sB[0][0])[idx] = Bb[idx];
  for (int idx = tid; idx < (TH + 1) * KD; idx += NT)
    (&sW[0][0])[idx] = Gb[idx];
  __syncthreads();

  // ---- qg[t][i] = sum_k Q[k][i] * g[t][k]   (Q = sV here, symmetric) ----
  for (int idx = tid; idx < (TH + 1) * KD; idx += NT) {
    const int t = idx >> 6, i = idx & 63;
    float s = 0.f;
    #pragma unroll 8
    for (int k = 0; k < KD; ++k) s += sV[k][i] * (&sW[0][0])[(t << 6) + k];
    sQG[t][i] = s;
  }
  __syncthreads();
  if (tid < KD) sv[tid] = sQG[TH][tid];   // v0 = Q @ goals[:, T]
  __syncthreads();

  const int i0 = ty << 2;
  const int j0 = tx << 2;

  for (int t = TH - 1; t >= 0; --t) {
    // ---- P1: W[i][j] = sum_k V[k][i]*A[k][j];  VB[i][u] = sum_k V[k][i]*B[k][u]
    {
      float acc[4][4] = {};
      float av0 = 0.f, av1 = 0.f, av2 = 0.f, av3 = 0.f;
      #pragma unroll 4
      for (int k = 0; k < KD; ++k) {
        const float4 a = *(const float4*)&sV[k][i0];
        const float4 c = *(const float4*)&sA[k][j0];
        const float bk = sB[k][tx];
        OUTER4P(acc, a, c)
        av0 += a.x * bk; av1 += a.y * bk; av2 += a.z * bk; av3 += a.w * bk;
      }
      #pragma unroll
      for (int r = 0; r < 4; ++r)
        *(float4*)&sW[i0 + r][j0] = make_float4(acc[r][0], acc[r][1], acc[r][2], acc[r][3]);
      sVB[i0 + 0][tx] = av0; sVB[i0 + 1][tx] = av1;
      sVB[i0 + 2][tx] = av2; sVB[i0 + 3][tx] = av3;
    }
    __syncthreads();

    // ---- P2: Vuu[u][w] = B^T VB + R;  BtW[u][j] = B^T W;  Btv = B^T v
    {
      float s = 0.f;
      #pragma unroll 8
      for (int k = 0; k < KD; ++k) s += sB[k][tx] * sVB[k][ty];
      sVuu[tx][ty] = s + Rb[tx * UD + ty];

      float a0 = 0.f, a1 = 0.f, a2 = 0.f, a3 = 0.f;
      const int jq = ty << 2;
      #pragma unroll 4
      for (int k = 0; k < KD; ++k) {
        const float bk = sB[k][tx];
        const float4 w = *(const float4*)&sW[k][jq];
        a0 += bk * w.x; a1 += bk * w.y; a2 += bk * w.z; a3 += bk * w.w;
      }
      *(float4*)&sBtW[tx][jq] = make_float4(a0, a1, a2, a3);

      if (tid < UD) {
        float s2 = 0.f;
        #pragma unroll 8
        for (int k = 0; k < KD; ++k) s2 += sB[k][tid] * sv[k];
        sBtv[tid] = s2;
      }
    }
    __syncthreads();

    // ---- P3: Cholesky of Vuu + M = L^{-1}, wave 0 in registers (no barriers)
    if (tid < 64) {
      const int u = tid & 15;
      float r[16];
      #pragma unroll
      for (int k = 0; k < 16; ++k) r[k] = sVuu[u][k];
      #pragma unroll
      for (int j = 0; j < 16; ++j) {
        float s = r[j];
        #pragma unroll
        for (int k = 0; k < j; ++k) s -= r[k] * __shfl(r[k], j); // L[j][k]
        const float dj  = sqrtf(__shfl(s, j));
        const float inv = 1.f / dj;
        r[j] = (u == j) ? dj : s * inv;   // lanes u<j hold garbage, never read
      }
      float idia[16];
      #pragma unroll
      for (int i = 0; i < 16; ++i) idia[i] = 1.f / __shfl(r[i], i);
      // lane c=u computes column c of M = L^{-1} (rows i<c come out 0)
      float x[16];
      #pragma unroll
      for (int i = 0; i < 16; ++i) {
        float s = (i == u) ? 1.f : 0.f;
        #pragma unroll
        for (int k = 0; k < i; ++k) s -= __shfl(r[k], i) * x[k]; // L[i][k]
        x[i] = s * idia[i];
      }
      if (tid < 16) {
        #pragma unroll
        for (int i = 0; i < 16; ++i) sMT[u][i] = x[i]; // sMT[c][i] = M[i][c]
      }
    }
    __syncthreads();

    // ---- P4: Vuu^{-1} = M^T M
    {
      float s = 0.f;
      #pragma unroll
      for (int i = 0; i < 16; ++i) s += sMT[tx][i] * sMT[ty][i];
      sVI[tx][ty] = s;
    }
    __syncthreads();

    // ---- P5: Kg = VI * BtW ; kg = VI * Btv
    {
      float a0 = 0.f, a1 = 0.f, a2 = 0.f, a3 = 0.f;
      const int jq = ty << 2;
      #pragma unroll
      for (int w = 0; w < UD; ++w) {
        const float vi = sVI[tx][w];
        const float4 bw = *(const float4*)&sBtW[w][jq];
        a0 += vi * bw.x; a1 += vi * bw.y; a2 += vi * bw.z; a3 += vi * bw.w;
      }
      *(float4*)&sKg[tx][jq] = make_float4(a0, a1, a2, a3);
      if (ty == 0) {
        float s = 0.f;
        #pragma unroll
        for (int w = 0; w < UD; ++w) s += sVI[tx][w] * sBtv[w];
        sKg[tx][64] = s;
      }
    }
    __syncthreads();

    // ---- copy out this step: 16 x 65 contiguous per (t,b)
    {
      const size_t obase = ((size_t)t * bsz + b) * (UD * 65);
      for (int idx = tid; idx < UD * 65; idx += NT)
        gOut[obase + idx] = sKg[idx / 65][idx % 65];
    }

    // ---- P6: V <- A^T W - BtW^T Kg + Q ;  v <- A^T v - Kg^T Btv + Q g_t
    if (t > 0) {
      float acc[4][4];
      #pragma unroll
      for (int r = 0; r < 4; ++r) {
        const float4 q = *(const float4*)&Qb[(i0 + r) * KD + j0];
        acc[r][0] = q.x; acc[r][1] = q.y; acc[r][2] = q.z; acc[r][3] = q.w;
      }
      #pragma unroll 4
      for (int k = 0; k < KD; ++k) {
        const float4 a = *(const float4*)&sA[k][i0];
        const float4 w = *(const float4*)&sW[k][j0];
        OUTER4P(acc, a, w)
      }
      #pragma unroll
      for (int u = 0; u < UD; ++u) {
        const float4 bw = *(const float4*)&sBtW[u][i0];
        const float4 kg = *(const float4*)&sKg[u][j0];
        OUTER4M(acc, bw, kg)
      }
      #pragma unroll
      for (int r = 0; r < 4; ++r)
        *(float4*)&sV[i0 + r][j0] = make_float4(acc[r][0], acc[r][1], acc[r][2], acc[r][3]);

      float vnew = 0.f;
      if (tid < KD) {
        vnew = sQG[t][tid];
        #pragma unroll 8
        for (int k = 0; k < KD; ++k) vnew += sA[k][tid] * sv[k];
        #pragma unroll
        for (int u = 0; u < UD; ++u) vnew -= sKg[u][tid] * sBtv[u];
      }
      __syncthreads();           // all reads of old sv / writes of sV done
      if (tid < KD) sv[tid] = vnew;
      // no barrier needed: next phase touching sv (P2) is after P1's barrier
    }
  }
}

extern "C" void kernel_launch(void* const* d_in, const int* in_sizes, int n_in,
                              void* d_out, int out_size, void* d_ws, size_t ws_size,
                              hipStream_t stream) {
  (void)n_in; (void)out_size; (void)d_ws; (void)ws_size;
  const float* A = (const float*)d_in[0];
  const float* B = (const float*)d_in[1];
  const float* Q = (const float*)d_in[2];
  const float* R = (const float*)d_in[3];
  const float* G = (const float*)d_in[4];
  float* out = (float*)d_out;
  const int bsz = in_sizes[3] / (UD * UD);   // R is bsz*16*16
  lqr_fp32<<<bsz, NT, 0, stream>>>(A, B, Q, R, G, out, bsz);
}

// Round 2
// 961.357 us; speedup vs baseline: 2.0234x; 2.0234x over previous
//
#include <hip/hip_runtime.h>

#define KD 64
#define UD 16
#define TH 30
#define NT 256

typedef short bf16x8 __attribute__((ext_vector_type(8)));
typedef float f32x4 __attribute__((ext_vector_type(4)));
typedef unsigned short u16x4 __attribute__((ext_vector_type(4)));

// split f into bf16 hi + bf16 lo (truncation; lo compensates) ~2^-17 rel
__device__ __forceinline__ void f2hl(float f, unsigned short& h, unsigned short& l) {
  unsigned int ub = __float_as_uint(f);
  h = (unsigned short)(ub >> 16);
  float fh = __uint_as_float(ub & 0xffff0000u);
  l = (unsigned short)(__float_as_uint(f - fh) >> 16);
}
__device__ __forceinline__ float rec(unsigned short h, unsigned short l) {
  return __uint_as_float((unsigned int)h << 16) + __uint_as_float((unsigned int)l << 16);
}

// row-major [R][64] ushort, granule-swizzled: elem (r,k) at r*64 + (((k>>3)^(r&7))<<3) + (k&7)
__device__ __forceinline__ bf16x8 ld64(const unsigned short* buf, int row, int kcg) {
  return *(const bf16x8*)(buf + row * 64 + ((kcg ^ (row & 7)) << 3));
}
// [R][16] ushort, unswizzled; K=16 frags: g>=2 -> zero (both X and Y zeroed: no 0*NaN)
__device__ __forceinline__ bf16x8 ld16(const unsigned short* buf, int row, int g) {
  if (g < 2) return *(const bf16x8*)(buf + row * 16 + (g << 3));
  bf16x8 z = {};
  return z;
}
__device__ __forceinline__ void st64_4(unsigned short* buf, int row, int col0, u16x4 v) {
  int off = row * 64 + ((((col0 >> 3)) ^ (row & 7)) << 3) + (col0 & 7);
  *(u16x4*)(buf + off) = v;
}
__device__ __forceinline__ void st16_4(unsigned short* buf, int row, int col0, u16x4 v) {
  *(u16x4*)(buf + row * 16 + col0) = v;
}
__device__ __forceinline__ void cvt4(f32x4 a, u16x4& h, u16x4& l) {
  #pragma unroll
  for (int i = 0; i < 4; ++i) {
    unsigned short hh, ll;
    f2hl(a[i], hh, ll);
    h[i] = hh; l[i] = ll;
  }
}

#define MFMA3(ACC, XH, XL, YH, YL)                                          \
  ACC = __builtin_amdgcn_mfma_f32_16x16x32_bf16(XH, YH, ACC, 0, 0, 0);      \
  ACC = __builtin_amdgcn_mfma_f32_16x16x32_bf16(XH, YL, ACC, 0, 0, 0);      \
  ACC = __builtin_amdgcn_mfma_f32_16x16x32_bf16(XL, YH, ACC, 0, 0, 0);

__global__ __launch_bounds__(NT, 2) void lqr_mfma(
    const float* __restrict__ gA, const float* __restrict__ gB,
    const float* __restrict__ gQ, const float* __restrict__ gR,
    const float* __restrict__ gG, float* __restrict__ gOut, int bsz)
{
  // hi/lo bf16 tiles (swizzled 64-wide ones noted)
  __shared__ unsigned short sVh[64 * 64], sVl[64 * 64];    // V row-major (symmetric), swz
  __shared__ unsigned short sAth[64 * 64], sAtl[64 * 64];  // At[i][k]=A[k][i], swz
  __shared__ unsigned short sWth[64 * 64], sWtl[64 * 64];  // Wt[j][i]=W[i][j], swz
  __shared__ unsigned short sBth[16 * 64], sBtl[16 * 64];  // Bt[u][k]=B[k][u], swz
  __shared__ unsigned short sVBh[16 * 64], sVBl[16 * 64];  // VBt[u][i]=VB[i][u], swz
  __shared__ unsigned short sBWh[64 * 16], sBWl[64 * 16];  // BtWt[j][u]=BtW[u][j]
  __shared__ unsigned short sKth[64 * 16], sKtl[64 * 16];  // -Kg^T: [j][u]=-Kg[u][j]
  __shared__ unsigned short sVIh[16 * 16], sVIl[16 * 16];  // Vuu^-1 row-major (sym)
  __shared__ float sQG[(TH + 1) * 64];
  __shared__ float sVuu[16 * 17];
  __shared__ float sMT[16 * 17];   // M=L^-1 columns; also v-partial scratch in phase E
  __shared__ float sKg[16 * 65];   // fp32 output staging (col 64 = kg)
  __shared__ float sv[64];
  __shared__ float sBtv[16];

  const int b    = blockIdx.x;
  const int tid  = threadIdx.x;
  const int lane = tid & 63;
  const int wv   = tid >> 6;   // wave 0..3
  const int r    = lane & 15;  // frag row/col id
  const int g    = lane >> 4;  // k-group 0..3

  const float* Ab = gA + (size_t)b * (64 * 64);
  const float* Bb = gB + (size_t)b * (64 * 16);
  const float* Qb = gQ + (size_t)b * (64 * 64);
  const float* Rb = gR + (size_t)b * (16 * 16);
  const float* Gb = gG + (size_t)b * ((TH + 1) * 64);

  // ---- stage + convert inputs ----
  for (int idx = tid; idx < 64 * 64; idx += NT) {
    int k = idx >> 6, i = idx & 63;
    unsigned short h, l;
    f2hl(Ab[idx], h, l);  // A[k][i] -> At[i][k]
    int offA = i * 64 + ((((k >> 3)) ^ (i & 7)) << 3) + (k & 7);
    sAth[offA] = h; sAtl[offA] = l;
    f2hl(Qb[idx], h, l);  // Q -> V (direct, symmetric)
    int offV = k * 64 + ((((i >> 3)) ^ (k & 7)) << 3) + (i & 7);
    sVh[offV] = h; sVl[offV] = l;
  }
  for (int idx = tid; idx < 64 * 16; idx += NT) {
    int k = idx >> 4, u = idx & 15;
    unsigned short h, l;
    f2hl(Bb[idx], h, l);  // B[k][u] -> Bt[u][k]
    int off = u * 64 + ((((k >> 3)) ^ (u & 7)) << 3) + (k & 7);
    sBth[off] = h; sBtl[off] = l;
  }
  __syncthreads();

  // ---- qg[t][i] = sum_k Q[i][k]*g[t][k]  (Q symmetric, reconstructed h+l) ----
  for (int idx = tid; idx < (TH + 1) * 64; idx += NT) {
    int t = idx >> 6, i = idx & 63;
    const float* gt = Gb + t * 64;
    float s = 0.f;
    #pragma unroll 8
    for (int k = 0; k < 64; ++k) {
      int off = i * 64 + ((((k >> 3)) ^ (i & 7)) << 3) + (k & 7);
      s += rec(sVh[off], sVl[off]) * gt[k];
    }
    sQG[idx] = s;
  }
  __syncthreads();
  if (tid < 64) sv[tid] = sQG[TH * 64 + tid];  // v0 = Q @ goals[:,T]

  // ---- per-thread constants: Q for G6 acc-init (tile coords fixed), R for Vuu ----
  f32x4 qreg[4];
  #pragma unroll
  for (int c = 0; c < 4; ++c) {
    #pragma unroll
    for (int rg = 0; rg < 4; ++rg)
      qreg[c][rg] = Qb[(16 * wv + 4 * g + rg) * 64 + 16 * c + r];
  }
  f32x4 rreg;
  #pragma unroll
  for (int rg = 0; rg < 4; ++rg) rreg[rg] = Rb[(4 * g + rg) * 16 + r];

  for (int t = TH - 1; t >= 0; --t) {
    // ===== Phase A: W = V*A -> Wt ; VB = V*B -> VBt  (wave wv: row-tile wv) =====
    {
      f32x4 accW0 = 0.f, accW1 = 0.f, accW2 = 0.f, accW3 = 0.f, accVB = 0.f;
      #pragma unroll
      for (int kc = 0; kc < 2; ++kc) {
        int kcg = 4 * kc + g;
        bf16x8 xh = ld64(sVh, 16 * wv + r, kcg);
        bf16x8 xl = ld64(sVl, 16 * wv + r, kcg);
        bf16x8 yh, yl;
        yh = ld64(sAth, 0 * 16 + r, kcg); yl = ld64(sAtl, 0 * 16 + r, kcg);
        MFMA3(accW0, xh, xl, yh, yl)
        yh = ld64(sAth, 1 * 16 + r, kcg); yl = ld64(sAtl, 1 * 16 + r, kcg);
        MFMA3(accW1, xh, xl, yh, yl)
        yh = ld64(sAth, 2 * 16 + r, kcg); yl = ld64(sAtl, 2 * 16 + r, kcg);
        MFMA3(accW2, xh, xl, yh, yl)
        yh = ld64(sAth, 3 * 16 + r, kcg); yl = ld64(sAtl, 3 * 16 + r, kcg);
        MFMA3(accW3, xh, xl, yh, yl)
        yh = ld64(sBth, r, kcg); yl = ld64(sBtl, r, kcg);
        MFMA3(accVB, xh, xl, yh, yl)
      }
      u16x4 h4, l4;
      cvt4(accW0, h4, l4); st64_4(sWth, 0 * 16 + r, 16 * wv + 4 * g, h4); st64_4(sWtl, 0 * 16 + r, 16 * wv + 4 * g, l4);
      cvt4(accW1, h4, l4); st64_4(sWth, 1 * 16 + r, 16 * wv + 4 * g, h4); st64_4(sWtl, 1 * 16 + r, 16 * wv + 4 * g, l4);
      cvt4(accW2, h4, l4); st64_4(sWth, 2 * 16 + r, 16 * wv + 4 * g, h4); st64_4(sWtl, 2 * 16 + r, 16 * wv + 4 * g, l4);
      cvt4(accW3, h4, l4); st64_4(sWth, 3 * 16 + r, 16 * wv + 4 * g, h4); st64_4(sWtl, 3 * 16 + r, 16 * wv + 4 * g, l4);
      cvt4(accVB, h4, l4); st64_4(sVBh, r, 16 * wv + 4 * g, h4); st64_4(sVBl, r, 16 * wv + 4 * g, l4);
    }
    __syncthreads();

    // ===== Phase B: Vuu = B^T*VB + R (w0) ; Btv = B^T v (w0) ; BtW = B^T*W (w1-3) =====
    if (wv == 0) {
      f32x4 accU = rreg, accBv = 0.f;
      #pragma unroll
      for (int kc = 0; kc < 2; ++kc) {
        int kcg = 4 * kc + g;
        bf16x8 xh = ld64(sBth, r, kcg);
        bf16x8 xl = ld64(sBtl, r, kcg);
        bf16x8 yh = ld64(sVBh, r, kcg);
        bf16x8 yl = ld64(sVBl, r, kcg);
        MFMA3(accU, xh, xl, yh, yl)
        bf16x8 vh = {}, vl = {};
        if (r == 0) {
          #pragma unroll
          for (int e = 0; e < 8; ++e) {
            unsigned short hh, ll;
            f2hl(sv[32 * kc + 8 * g + e], hh, ll);
            vh[e] = (short)hh; vl[e] = (short)ll;
          }
        }
        MFMA3(accBv, xh, xl, vh, vl)
      }
      #pragma unroll
      for (int rg = 0; rg < 4; ++rg) sVuu[(4 * g + rg) * 17 + r] = accU[rg];
      if (r == 0) {
        #pragma unroll
        for (int rg = 0; rg < 4; ++rg) sBtv[4 * g + rg] = accBv[rg];
      }
    } else {
      #pragma unroll
      for (int ci = 0; ci < 2; ++ci) {
        int c = (ci == 0) ? (wv - 1) : ((wv == 1) ? 3 : -1);
        if (c >= 0) {
          f32x4 acc = 0.f;
          #pragma unroll
          for (int kc = 0; kc < 2; ++kc) {
            int kcg = 4 * kc + g;
            bf16x8 xh = ld64(sBth, r, kcg);
            bf16x8 xl = ld64(sBtl, r, kcg);
            bf16x8 yh = ld64(sWth, 16 * c + r, kcg);
            bf16x8 yl = ld64(sWtl, 16 * c + r, kcg);
            MFMA3(acc, xh, xl, yh, yl)
          }
          u16x4 h4, l4; cvt4(acc, h4, l4);
          st16_4(sBWh, 16 * c + r, 4 * g, h4);
          st16_4(sBWl, 16 * c + r, 4 * g, l4);
        }
      }
    }
    __syncthreads();

    // ===== Phase C1: Cholesky Vuu = L L^T, M = L^-1 (wave 0 registers) =====
    if (wv == 0) {
      const int u = lane & 15;
      float rr[16];
      #pragma unroll
      for (int k = 0; k < 16; ++k) rr[k] = sVuu[u * 17 + k];
      #pragma unroll
      for (int j = 0; j < 16; ++j) {
        float s = rr[j];
        #pragma unroll
        for (int k = 0; k < j; ++k) s -= rr[k] * __shfl(rr[k], j);
        const float dj  = sqrtf(__shfl(s, j));
        const float inv = 1.f / dj;
        rr[j] = (u == j) ? dj : s * inv;
      }
      float idia[16];
      #pragma unroll
      for (int i = 0; i < 16; ++i) idia[i] = 1.f / __shfl(rr[i], i);
      float x[16];
      #pragma unroll
      for (int i = 0; i < 16; ++i) {
        float s = (i == u) ? 1.f : 0.f;
        #pragma unroll
        for (int k = 0; k < i; ++k) s -= __shfl(rr[k], i) * x[k];
        x[i] = s * idia[i];
      }
      if (lane < 16) {
        #pragma unroll
        for (int i = 0; i < 16; ++i) sMT[u * 17 + i] = x[i];  // sMT[c][i]=M[i][c]
      }
    }
    __syncthreads();

    // ===== Phase C2: VI = M^T M -> bf16 hi/lo =====
    {
      const int a2 = tid & 15, b2 = tid >> 4;
      float s = 0.f;
      #pragma unroll
      for (int i = 0; i < 16; ++i) s += sMT[a2 * 17 + i] * sMT[b2 * 17 + i];
      unsigned short h, l; f2hl(s, h, l);
      sVIh[a2 * 16 + b2] = h; sVIl[a2 * 16 + b2] = l;
    }
    __syncthreads();

    // ===== Phase D: Kg = VI*BtW (wave wv: col-tile wv) ; kg = VI*Btv =====
    {
      f32x4 acc = 0.f;
      bf16x8 xh = ld16(sVIh, r, g);
      bf16x8 xl = ld16(sVIl, r, g);
      bf16x8 yh = ld16(sBWh, 16 * wv + r, g);
      bf16x8 yl = ld16(sBWl, 16 * wv + r, g);
      MFMA3(acc, xh, xl, yh, yl)
      u16x4 h4, l4;
      f32x4 nacc = -acc;
      cvt4(nacc, h4, l4);
      st16_4(sKth, 16 * wv + r, 4 * g, h4);  // store -Kg^T
      st16_4(sKtl, 16 * wv + r, 4 * g, l4);
      #pragma unroll
      for (int rg = 0; rg < 4; ++rg)
        sKg[(4 * g + rg) * 65 + (16 * wv + r)] = acc[rg];
      if (tid >= 64 && tid < 80) {
        const int uu = tid - 64;
        float s = 0.f;
        #pragma unroll
        for (int w2 = 0; w2 < 16; ++w2)
          s += rec(sVIh[uu * 16 + w2], sVIl[uu * 16 + w2]) * sBtv[w2];
        sKg[uu * 65 + 64] = s;
      }
    }
    __syncthreads();

    // ===== Phase E: copy out ; Vnew = Q + A^T W - BtW^T Kg ; v update =====
    {
      const size_t obase = ((size_t)t * bsz + b) * (16 * 65);
      for (int idx = tid; idx < 16 * 65; idx += NT)
        gOut[obase + idx] = sKg[idx];
    }
    if (t > 0) {
      f32x4 acc0 = qreg[0], acc1 = qreg[1], acc2 = qreg[2], acc3 = qreg[3];
      {
        bf16x8 x2h = ld16(sBWh, 16 * wv + r, g);
        bf16x8 x2l = ld16(sBWl, 16 * wv + r, g);
        bf16x8 yh, yl;
        yh = ld16(sKth, 0 * 16 + r, g); yl = ld16(sKtl, 0 * 16 + r, g);
        MFMA3(acc0, x2h, x2l, yh, yl)
        yh = ld16(sKth, 1 * 16 + r, g); yl = ld16(sKtl, 1 * 16 + r, g);
        MFMA3(acc1, x2h, x2l, yh, yl)
        yh = ld16(sKth, 2 * 16 + r, g); yl = ld16(sKtl, 2 * 16 + r, g);
        MFMA3(acc2, x2h, x2l, yh, yl)
        yh = ld16(sKth, 3 * 16 + r, g); yl = ld16(sKtl, 3 * 16 + r, g);
        MFMA3(acc3, x2h, x2l, yh, yl)
      }
      #pragma unroll
      for (int kc = 0; kc < 2; ++kc) {
        int kcg = 4 * kc + g;
        bf16x8 xh = ld64(sAth, 16 * wv + r, kcg);
        bf16x8 xl = ld64(sAtl, 16 * wv + r, kcg);
        bf16x8 yh, yl;
        yh = ld64(sWth, 0 * 16 + r, kcg); yl = ld64(sWtl, 0 * 16 + r, kcg);
        MFMA3(acc0, xh, xl, yh, yl)
        yh = ld64(sWth, 1 * 16 + r, kcg); yl = ld64(sWtl, 1 * 16 + r, kcg);
        MFMA3(acc1, xh, xl, yh, yl)
        yh = ld64(sWth, 2 * 16 + r, kcg); yl = ld64(sWtl, 2 * 16 + r, kcg);
        MFMA3(acc2, xh, xl, yh, yl)
        yh = ld64(sWth, 3 * 16 + r, kcg); yl = ld64(sWtl, 3 * 16 + r, kcg);
        MFMA3(acc3, xh, xl, yh, yl)
      }
      // v partials: v_new[i] = qg[t][i] + sum_k At[i][k] v[k] - sum_u Kg[u][i] Btv[u]
      {
        const int i = tid & 63, q = tid >> 6;
        float s = (q == 0) ? sQG[t * 64 + i] : 0.f;
        #pragma unroll
        for (int kk = 0; kk < 16; ++kk) {
          int k = 16 * q + kk;
          int off = i * 64 + ((((k >> 3)) ^ (i & 7)) << 3) + (k & 7);
          s += rec(sAth[off], sAtl[off]) * sv[k];
        }
        #pragma unroll
        for (int uu = 0; uu < 4; ++uu)
          s -= sKg[(4 * q + uu) * 65 + i] * sBtv[4 * q + uu];
        sMT[q * 64 + i] = s;  // sMT dead after C2 -> partial scratch
      }
      // write Vnew transposed (V symmetric) -> sV
      u16x4 h4, l4;
      cvt4(acc0, h4, l4); st64_4(sVh, 0 * 16 + r, 16 * wv + 4 * g, h4); st64_4(sVl, 0 * 16 + r, 16 * wv + 4 * g, l4);
      cvt4(acc1, h4, l4); st64_4(sVh, 1 * 16 + r, 16 * wv + 4 * g, h4); st64_4(sVl, 1 * 16 + r, 16 * wv + 4 * g, l4);
      cvt4(acc2, h4, l4); st64_4(sVh, 2 * 16 + r, 16 * wv + 4 * g, h4); st64_4(sVl, 2 * 16 + r, 16 * wv + 4 * g, l4);
      cvt4(acc3, h4, l4); st64_4(sVh, 3 * 16 + r, 16 * wv + 4 * g, h4); st64_4(sVl, 3 * 16 + r, 16 * wv + 4 * g, l4);
      __syncthreads();
      if (tid < 64)
        sv[tid] = sMT[tid] + sMT[64 + tid] + sMT[128 + tid] + sMT[192 + tid];
    }
  }
}

extern "C" void kernel_launch(void* const* d_in, const int* in_sizes, int n_in,
                              void* d_out, int out_size, void* d_ws, size_t ws_size,
                              hipStream_t stream) {
  (void)n_in; (void)out_size; (void)d_ws; (void)ws_size;
  const float* A = (const float*)d_in[0];
  const float* B = (const float*)d_in[1];
  const float* Q = (const float*)d_in[2];
  const float* R = (const float*)d_in[3];
  const float* G = (const float*)d_in[4];
  float* out = (float*)d_out;
  const int bsz = in_sizes[3] / (UD * UD);  // R is bsz*16*16
  lqr_mfma<<<bsz, NT, 0, stream>>>(A, B, Q, R, G, out, bsz);
}